// Round 11
// baseline (257.640 us; speedup 1.0000x reference)
//
#include <hip/hip_runtime.h>
#include <math.h>

#define NROWS 131072
#define DIM   64
#define KCENT 1024
#define DECAY 0.99f
#define EPS_  1e-5f

typedef unsigned int u32;
typedef unsigned short u16;
typedef __attribute__((ext_vector_type(8))) short short8b;
typedef __attribute__((ext_vector_type(16))) float floatx16;

// ---------------- ws layout (float elements) ----------------
// csum    [K*D]    @ 0        (zeroed by k_ctrans)
// cnt     [K]      @ 65536    (int, zeroed by k_ctrans)
// cs      [K]      @ 66560
// cnewT   [K*D]    @ 67584
// ind     [N]      @ 133120   (int)
// pk      [N]      @ 264192   (int2: {row, cluster} in sorted order)
// cursor16[K*16]   @ 527360   (int, 64B-spread atomic cursors)
// centB   [K*68]   @ 543744   (u32: bf16 hi 32dw | lo 32dw | csq@64 | pad; 272B rows)

__device__ inline u16 bf16rne(float f) {
    u32 u = __float_as_uint(f);
    return (u16)((u + 0x7FFFu + ((u >> 16) & 1u)) >> 16);
}

// ---------- K1: centroid transpose/split + zero csum/cnt ----------
__global__ void k_ctrans(const float* __restrict__ cent, u32* __restrict__ centB,
                         float* __restrict__ zero_base) {
    int tid = blockIdx.x * 256 + threadIdx.x;   // 0..1023
    float4 z = make_float4(0.f, 0.f, 0.f, 0.f);
    for (int i = tid; i < 16640; i += 1024) ((float4*)zero_base)[i] = z;

    int k = tid;
    u32* row = centB + (size_t)k * 68;
    float csq = 0.f;
#pragma unroll
    for (int d0 = 0; d0 < 32; ++d0) {
        float f0 = cent[(2 * d0) * KCENT + k];      // coalesced across lanes
        float f1 = cent[(2 * d0 + 1) * KCENT + k];
        u16 h0 = bf16rne(f0), h1 = bf16rne(f1);
        u16 s0 = bf16rne(f0 - __uint_as_float((u32)h0 << 16));
        u16 s1 = bf16rne(f1 - __uint_as_float((u32)h1 << 16));
        csq = fmaf(f0, f0, fmaf(f1, f1, csq));
        row[d0]      = (u32)h0 | ((u32)h1 << 16);   // hi
        row[32 + d0] = (u32)s0 | ((u32)s1 << 16);   // lo
    }
    row[64] = __float_as_uint(csq);
}

// ---------- K2: MFMA assignment, 3-term split, M=32/wave, 1 barrier/tile ----
// dot ~= xh.ch + xh.cl + xl.ch; C layout (m74/m101):
// col=lane&31, row=(reg&3)+8*(reg>>2)+4*(lane>>5).
// Double-buffer invariant: read of buf[b] (tile t) and next write (tile t+2)
// are separated by the tile-t+1 barrier -> ONE barrier per tile suffices.
__global__ __launch_bounds__(256, 4) void k_assign(
    const float* __restrict__ x, const u32* __restrict__ centB,
    int* __restrict__ ind, int* __restrict__ cnt) {
    __shared__ __align__(16) char buf[2][17408];   // 64 cents x 272B
    __shared__ int hist[KCENT];
    const int tid  = threadIdx.x;
    const int lane = tid & 63;
    const int wid  = tid >> 6;
    const int half = lane >> 5;
    const int nl   = lane & 31;
#pragma unroll
    for (int i = 0; i < KCENT / 256; ++i) hist[tid + i * 256] = 0;

    const int rowbase = blockIdx.x * 128 + wid * 32;
    const float* xr = x + (size_t)(rowbase + nl) * DIM;

    // A-frags: 4 hi + 4 lo (dims t4*16+half*8 .. +8)
    short8b ah[4], al[4];
#pragma unroll
    for (int t4 = 0; t4 < 4; ++t4) {
        int d0 = t4 * 16 + half * 8;
        float4 f0 = *(const float4*)(xr + d0);
        float4 f1 = *(const float4*)(xr + d0 + 4);
        float fv[8] = {f0.x, f0.y, f0.z, f0.w, f1.x, f1.y, f1.z, f1.w};
        short8b va, vb;
#pragma unroll
        for (int j = 0; j < 8; ++j) {
            u16 h = bf16rne(fv[j]);
            float lo = fv[j] - __uint_as_float((u32)h << 16);
            va[j] = (short)h;
            vb[j] = (short)bf16rne(lo);
        }
        ah[t4] = va;
        al[t4] = vb;
    }

    float best[16];
    int   bidx[16];
#pragma unroll
    for (int r = 0; r < 16; ++r) { best[r] = 3.402823466e38f; bidx[r] = 0; }

    // tile = 64 cents = 1088 granules of 16B; 16 tiles total
    const float4* gsrc = (const float4*)centB;
    float4 pf0, pf1, pf2, pf3, pft;
    pf0 = gsrc[tid];
    pf1 = gsrc[tid + 256];
    pf2 = gsrc[tid + 512];
    pf3 = gsrc[tid + 768];
    if (tid < 64) pft = gsrc[tid + 1024];

    for (int kt = 0; kt < 16; ++kt) {
        char* b = buf[kt & 1];
        *(float4*)(b + (size_t)tid * 16)         = pf0;
        *(float4*)(b + (size_t)(tid + 256) * 16) = pf1;
        *(float4*)(b + (size_t)(tid + 512) * 16) = pf2;
        *(float4*)(b + (size_t)(tid + 768) * 16) = pf3;
        if (tid < 64) *(float4*)(b + (size_t)(tid + 1024) * 16) = pft;
        __syncthreads();                             // the ONLY barrier per tile
        if (kt < 15) {                               // prefetch next tile
            size_t gb = (size_t)(kt + 1) * 1088;
            pf0 = gsrc[gb + tid];
            pf1 = gsrc[gb + tid + 256];
            pf2 = gsrc[gb + tid + 512];
            pf3 = gsrc[gb + tid + 768];
            if (tid < 64) pft = gsrc[gb + tid + 1024];
        }

#pragma unroll
        for (int sub = 0; sub < 2; ++sub) {
            const char* base = b + (size_t)(sub * 32 + nl) * 272 + half * 16;
            short8b bh[4], bl[4];
#pragma unroll
            for (int t4 = 0; t4 < 4; ++t4) bh[t4] = *(const short8b*)(base + t4 * 32);
#pragma unroll
            for (int t4 = 0; t4 < 4; ++t4) bl[t4] = *(const short8b*)(base + 128 + t4 * 32);
            float cq  = *(const float*)(b + (size_t)(sub * 32 + nl) * 272 + 256);
            int  cidx = kt * 64 + sub * 32 + nl;

            floatx16 acc;
#pragma unroll
            for (int i = 0; i < 16; ++i) acc[i] = 0.f;
#pragma unroll
            for (int t4 = 0; t4 < 4; ++t4)
                acc = __builtin_amdgcn_mfma_f32_32x32x16_bf16(ah[t4], bh[t4], acc, 0, 0, 0);
#pragma unroll
            for (int t4 = 0; t4 < 4; ++t4)
                acc = __builtin_amdgcn_mfma_f32_32x32x16_bf16(ah[t4], bl[t4], acc, 0, 0, 0);
#pragma unroll
            for (int t4 = 0; t4 < 4; ++t4)
                acc = __builtin_amdgcn_mfma_f32_32x32x16_bf16(al[t4], bh[t4], acc, 0, 0, 0);
#pragma unroll
            for (int r = 0; r < 16; ++r) {
                float dist = fmaf(-2.0f, acc[r], cq);
                if (dist < best[r]) { best[r] = dist; bidx[r] = cidx; }
            }
        }
        // no trailing barrier (see invariant above)
    }

    // cross-lane argmin within each 32-lane half
#pragma unroll
    for (int r = 0; r < 16; ++r) {
        float b0 = best[r]; int i0 = bidx[r];
#pragma unroll
        for (int m = 1; m < 32; m <<= 1) {
            float bp = __shfl_xor(b0, m, 64);
            int   ip = __shfl_xor(i0, m, 64);
            if (bp < b0 || (bp == b0 && ip < i0)) { b0 = bp; i0 = ip; }
        }
        best[r] = b0; bidx[r] = i0;
    }
    if (nl == 0) {
#pragma unroll
        for (int r = 0; r < 16; ++r) {
            int m = (r & 3) + 8 * (r >> 2) + 4 * half;
            ind[rowbase + m] = bidx[r];
            atomicAdd(&hist[bidx[r]], 1);
        }
    }
    __syncthreads();
#pragma unroll
    for (int i = 0; i < KCENT / 256; ++i) {
        int bkt = tid + i * 256;
        int v = hist[bkt];
        if (v) atomicAdd(&cnt[bkt], v);
    }
}

// ---------- K3: EMA stats + Laplace cs + prefix sum (shuffle-scan) ----------
__global__ void k_scan(const float* __restrict__ cluster_size,
                       const int* __restrict__ cnt,
                       float* __restrict__ cs,
                       int* __restrict__ start_unused, int* __restrict__ cursor16,
                       float* __restrict__ loss) {
    __shared__ float wsumf[16];
    __shared__ int   wtot[16];
    __shared__ int   woff[16];
    __shared__ float ftot_s;
    const int t = threadIdx.x;           // 0..1023
    const int lane = t & 63, w = t >> 6;
    const int c = cnt[t];
    float cls = DECAY * cluster_size[t] + (1.0f - DECAY) * (float)c;

    float s = cls;
#pragma unroll
    for (int m = 1; m < 64; m <<= 1) s += __shfl_xor(s, m, 64);
    int inc = c;
#pragma unroll
    for (int m = 1; m < 64; m <<= 1) {
        int u = __shfl_up(inc, m, 64);
        if (lane >= m) inc += u;
    }
    if (lane == 0)  wsumf[w] = s;
    if (lane == 63) wtot[w]  = inc;
    __syncthreads();
    if (t == 0) {
        int run = 0; float ft = 0.f;
#pragma unroll
        for (int i = 0; i < 16; ++i) { woff[i] = run; run += wtot[i]; ft += wsumf[i]; }
        ftot_s = ft;
        loss[0] = 0.f;                 // fold loss-slot zeroing here
    }
    __syncthreads();
    float ntot = ftot_s;
    cs[t] = (cls + EPS_) / (ntot + KCENT * EPS_) * ntot;
    int excl = woff[w] + inc - c;
    cursor16[t * 16] = excl;
}

// ---------- K4: scatter with block-aggregated ranks ----------
__global__ __launch_bounds__(256) void k_scatter(
    const int* __restrict__ ind, int* __restrict__ cursor16,
    int2* __restrict__ pk) {
    __shared__ int lh[KCENT];
#pragma unroll
    for (int i = 0; i < KCENT / 256; ++i) lh[threadIdx.x + i * 256] = 0;
    __syncthreads();

    const int n  = blockIdx.x * 256 + threadIdx.x;
    const int bi = ind[n];
    const int rank = atomicAdd(&lh[bi], 1);   // LDS atomic: old = my rank
    __syncthreads();

#pragma unroll
    for (int i = 0; i < KCENT / 256; ++i) {
        int k = threadIdx.x + i * 256;
        int c = lh[k];
        int base = 0;
        if (c) base = atomicAdd(&cursor16[k * 16], c);  // one per distinct cluster
        lh[k] = base;
    }
    __syncthreads();

    pk[lh[bi] + rank] = make_int2(n, bi);
}

// ---------- K5: segment sum over uniform 32-row wave-windows ----------
__global__ __launch_bounds__(256) void k_segsum(
    const float* __restrict__ x, const int2* __restrict__ pk,
    float* __restrict__ csum) {
    const int wgid = blockIdx.x * 4 + (threadIdx.x >> 6);  // 0..4095
    const int lane = threadIdx.x & 63;
    const int r0   = wgid * 32;

    float acc = 0.f;
    int cur = pk[r0].y;
#pragma unroll 4
    for (int r = r0; r < r0 + 32; r += 2) {
        int2 a = pk[r];                   // wave-uniform -> scalar 8B load
        int2 b = pk[r + 1];
        float v0 = x[(size_t)a.x * DIM + lane];   // coalesced 256B/row
        float v1 = x[(size_t)b.x * DIM + lane];
        if (a.y != cur) {
            atomicAdd(&csum[(size_t)cur * DIM + lane], acc);
            acc = 0.f; cur = a.y;
        }
        acc += v0;
        if (b.y != cur) {
            atomicAdd(&csum[(size_t)cur * DIM + lane], acc);
            acc = 0.f; cur = b.y;
        }
        acc += v1;
    }
    atomicAdd(&csum[(size_t)cur * DIM + lane], acc);
}

// ---------- K6: centroids_new, stored transposed [K][D] ----------
__global__ void k_newcent(const float* __restrict__ avg,
                          const float* __restrict__ csum,
                          const float* __restrict__ cs,
                          float* __restrict__ cnewT) {
    int idx = blockIdx.x * blockDim.x + threadIdx.x;  // = k*64 + d
    int k = idx >> 6, d = idx & 63;
    float v = DECAY * avg[d * KCENT + k] + (1.0f - DECAY) * csum[idx];
    cnewT[idx] = v / cs[k];
}

// ---------- K7: gather quantized rows + MSE loss ----------
__global__ __launch_bounds__(256) void k_out(
    const float* __restrict__ x, const int* __restrict__ ind,
    const float* __restrict__ cnewT, float* __restrict__ out,
    float* __restrict__ loss) {
    const int tid = threadIdx.x;
    const int l16 = tid & 15;
    float p = 0.f;

    for (int g = blockIdx.x; g < NROWS / 16; g += 2048) {
        int row = g * 16 + (tid >> 4);
        int k = ind[row];
        float4 q  = ((const float4*)(cnewT + (size_t)k * DIM))[l16];
        float4 xw = ((const float4*)(x + (size_t)row * DIM))[l16];
        ((float4*)(out + (size_t)row * DIM))[l16] = q;
        float dx = xw.x - q.x, dy = xw.y - q.y, dz = xw.z - q.z, dw = xw.w - q.w;
        p += dx * dx + dy * dy + dz * dz + dw * dw;
    }

    __shared__ float red[256];
    red[tid] = p;
    __syncthreads();
    for (int off = 128; off > 0; off >>= 1) {
        if (tid < off) red[tid] += red[tid + off];
        __syncthreads();
    }
    if (tid == 0)
        atomicAdd(loss, red[0] * (1.0f / ((float)NROWS * (float)DIM)));
}

extern "C" void kernel_launch(void* const* d_in, const int* in_sizes, int n_in,
                              void* d_out, int out_size, void* d_ws, size_t ws_size,
                              hipStream_t stream) {
    const float* x            = (const float*)d_in[0];
    const float* cent         = (const float*)d_in[1];
    const float* cluster_size = (const float*)d_in[2];
    const float* avg          = (const float*)d_in[3];
    float* out = (float*)d_out;

    float* ws       = (float*)d_ws;
    float* csum     = ws;                     // K*D
    int*   cnt      = (int*)(ws + 65536);     // K
    float* cs       = ws + 66560;             // K
    float* cnewT    = ws + 67584;             // K*D
    int*   ind      = (int*)(ws + 133120);    // N
    int2*  pk       = (int2*)(ws + 264192);   // N int2
    int*   cursor16 = (int*)(ws + 527360);    // 16K
    u32*   centB    = (u32*)(ws + 543744);    // K*68
    float* loss     = out + (size_t)NROWS * DIM;

    k_ctrans <<<KCENT / 256, 256, 0, stream>>>(cent, centB, csum);
    k_assign <<<NROWS / 128, 256, 0, stream>>>(x, centB, ind, cnt);
    k_scan   <<<1, KCENT, 0, stream>>>(cluster_size, cnt, cs, nullptr, cursor16, loss);
    k_scatter<<<NROWS / 256, 256, 0, stream>>>(ind, cursor16, pk);
    k_segsum <<<NROWS / 128, 256, 0, stream>>>(x, pk, csum);
    k_newcent<<<(KCENT * DIM) / 256, 256, 0, stream>>>(avg, csum, cs, cnewT);
    k_out    <<<2048, 256, 0, stream>>>(x, ind, cnewT, out, loss);
}